// Round 7
// baseline (2726.792 us; speedup 1.0000x reference)
//
#include <hip/hip_runtime.h>

// V=50000, E=64, B=64, T=1024, F=128, H=128, WIN=3, PAD=1
// K = WIN*E = 192 fused reduction dim; G = 2*3H = 768 projection outputs

typedef __attribute__((ext_vector_type(8))) unsigned short ushort8;
typedef __attribute__((ext_vector_type(8))) short bf16x8;   // MFMA bf16 frag (guide §3)
typedef __attribute__((ext_vector_type(4))) float f32x4;

__device__ __forceinline__ unsigned short f2bf(float f) {
  unsigned int u = __float_as_uint(f);
  u += 0x7fffu + ((u >> 16) & 1u);   // RNE
  return (unsigned short)(u >> 16);
}
__device__ __forceinline__ float bf2f(unsigned short us) {
  return __uint_as_float(((unsigned int)us) << 16);
}

// ---------------------------------------------------------------------------
// K0: CWb[g][k] = bf16( sum_f Wih[g][f]*conv_w[f][k] );
//     xbias[g] = b_ih[g] + Wih[g]·conv_b  (+ b_hh[g] folded for r,z gates only —
//     the n-gate hidden bias enters inside r*(hn+bh2) and cannot be folded).
__global__ void k0_fuse(const float* __restrict__ conv_w, const float* __restrict__ conv_b,
                        const float* __restrict__ w_ih_f, const float* __restrict__ b_ih_f,
                        const float* __restrict__ w_ih_b, const float* __restrict__ b_ih_b,
                        const float* __restrict__ b_hh_f, const float* __restrict__ b_hh_b,
                        unsigned short* __restrict__ CWb, float* __restrict__ xbias) {
  int flat = blockIdx.x * 256 + threadIdx.x;
  if (flat >= 768 * 192) return;
  int g = flat / 192, k = flat % 192;
  const float* wih = (g < 384) ? w_ih_f : w_ih_b;
  int gg = (g < 384) ? g : g - 384;
  float acc = 0.f;
  for (int f = 0; f < 128; ++f) acc += wih[gg * 128 + f] * conv_w[f * 192 + k];
  CWb[g * 192 + k] = f2bf(acc);
  if (k == 0) {
    const float* bih = (g < 384) ? b_ih_f : b_ih_b;
    const float* bhh = (g < 384) ? b_hh_f : b_hh_b;
    float bb = bih[gg];
    if (gg < 256) bb += bhh[gg];        // fold hidden bias for r,z gates
    for (int f = 0; f < 128; ++f) bb += wih[gg * 128 + f] * conv_b[f];
    xbias[g] = bb;
  }
}

// ---------------------------------------------------------------------------
// K1: xp[b][t][g] = bf16( xbias[g] + sum_k A[t][k]*CW[g][k] ) via MFMA bf16.
//     Block = 128t x 128g, K=192. 4 waves in 2x2, wave tile 64x64 (4x4 frags).
__global__ __launch_bounds__(256) void k1_gemm(const int* __restrict__ ipts,
                                               const float* __restrict__ emb,
                                               const unsigned short* __restrict__ CWb,
                                               const float* __restrict__ xbias,
                                               unsigned short* __restrict__ xp) {
  __shared__ __align__(16) unsigned short xs[130][72];    // bf16 emb rows, stride 144B
  __shared__ __align__(16) unsigned short wsb[128][200];  // bf16 CW chunk, stride 400B
  const int bid = blockIdx.x;
  const int gb = bid % 6, tb = bid / 6;
  const int b = tb >> 3, t0 = (tb & 7) << 7, g0 = gb << 7;
  const int tid = threadIdx.x;

  for (int c = tid; c < 130 * 16; c += 256) {   // stage A (gather + f32->bf16)
    int row = c >> 4, cc = c & 15;
    int t = t0 - 1 + row;
    float4 v = make_float4(0.f, 0.f, 0.f, 0.f);
    if (t >= 0 && t < 1024) {
      int tok = ipts[b * 1024 + t];
      v = *reinterpret_cast<const float4*>(emb + (size_t)tok * 64 + cc * 4);
    }
    ushort4 pv;
    pv.x = f2bf(v.x); pv.y = f2bf(v.y); pv.z = f2bf(v.z); pv.w = f2bf(v.w);
    *reinterpret_cast<ushort4*>(&xs[row][cc * 4]) = pv;
  }
  for (int c = tid; c < 128 * 24; c += 256) {   // stage B chunk
    int g = c / 24, cc = c % 24;
    *reinterpret_cast<ushort8*>(&wsb[g][cc * 8]) =
        *reinterpret_cast<const ushort8*>(CWb + (size_t)(g0 + g) * 192 + cc * 8);
  }
  __syncthreads();

  const int lane = tid & 63, wid = tid >> 6;
  const int wy = wid >> 1, wx = wid & 1;
  const int ln15 = lane & 15, lhi = lane >> 4;

  f32x4 acc[4][4];
#pragma unroll
  for (int i = 0; i < 4; ++i)
#pragma unroll
    for (int j = 0; j < 4; ++j) acc[i][j] = (f32x4){0.f, 0.f, 0.f, 0.f};

#pragma unroll
  for (int kk = 0; kk < 6; ++kk) {
    const int w = kk >> 1;                    // k = w*64 + e, never straddles w
    const int e0 = (kk & 1) * 32 + lhi * 8;
    const int k0 = kk * 32 + lhi * 8;
    bf16x8 a[4], bb[4];
#pragma unroll
    for (int i = 0; i < 4; ++i)
      a[i] = *reinterpret_cast<const bf16x8*>(&xs[wy * 64 + i * 16 + ln15 + w][e0]);
#pragma unroll
    for (int j = 0; j < 4; ++j)
      bb[j] = *reinterpret_cast<const bf16x8*>(&wsb[wx * 64 + j * 16 + ln15][k0]);
#pragma unroll
    for (int i = 0; i < 4; ++i)
#pragma unroll
      for (int j = 0; j < 4; ++j)
        acc[i][j] = __builtin_amdgcn_mfma_f32_16x16x32_bf16(a[i], bb[j], acc[i][j], 0, 0, 0);
  }

  float bias[4];
#pragma unroll
  for (int j = 0; j < 4; ++j) bias[j] = xbias[g0 + wx * 64 + j * 16 + ln15];

  unsigned short* outp = xp + (size_t)(b * 1024 + t0 + wy * 64) * 768 + g0 + wx * 64;
#pragma unroll
  for (int i = 0; i < 4; ++i)
#pragma unroll
    for (int r = 0; r < 4; ++r) {
      int m = i * 16 + lhi * 4 + r;           // C/D: col=lane&15, row=(lane>>4)*4+reg
#pragma unroll
      for (int j = 0; j < 4; ++j)
        outp[(size_t)m * 768 + j * 16 + ln15] = f2bf(acc[i][j][r] + bias[j]);
    }
}

// ---------------------------------------------------------------------------
// select one of 4 f32x4 by lane-varying index (c&3) — 12 v_cndmask, no scratch
__device__ __forceinline__ f32x4 sel4(f32x4 q0, f32x4 q1, f32x4 q2, f32x4 q3, int c) {
  f32x4 a = (c & 1) ? q1 : q0;
  f32x4 b = (c & 1) ? q3 : q2;
  return (c & 2) ? b : a;
}

// ---------------------------------------------------------------------------
// K2: GRU scan — ONE WAVE per (batch, direction), 128 single-wave blocks,
//     ZERO barriers. gh = W_hh·h as MFMA with h BROADCAST into all 16 B-cols:
//     every C column holds the same dot, so r,z,n for row j live in one lane
//     (tiles m, m+8, m+16) -> register-local gate combine.
//     W_hh resident in 384 VGPRs as 96 A-frags (2 phases x 3 gates x 4 slices
//     x 4 k-tiles). h (128 bf16) in 256B wave-private LDS: 4 ds_read_b128
//     broadcast per step + 2 ds_write_b64; sync = s_waitcnt lgkmcnt only.
//     x-gates: 6 global b64 loads prefetched one step ahead (xp L3-resident).
//     Lane (g=lane>>4, c=lane&15): phase A combines rows jA=16*(c&3)+4g..+3,
//     phase B rows jB=64+jA; writers cA: c<4, cB: 4<=c<8.
__global__ __launch_bounds__(64) void k2_scan(
    const int* __restrict__ seqlen, const float* __restrict__ hidden,
    const float* __restrict__ w_hh_f, const float* __restrict__ b_hh_f,
    const float* __restrict__ w_hh_b, const float* __restrict__ b_hh_b,
    const unsigned short* __restrict__ xp, float* __restrict__ mot) {
  __shared__ __align__(16) unsigned short hL[128];   // h as bf16 (wave-private)
  const int lane = threadIdx.x;
  const int b = blockIdx.x & 63, dir = blockIdx.x >> 6;
  const int g = lane >> 4, c = lane & 15, cm = c & 3;
  const float* whh = dir ? w_hh_b : w_hh_f;
  const float* bhh = dir ? b_hh_b : b_hh_f;
  const int jA = 16 * cm + 4 * g;   // phase-A rows jA..jA+3
  const int jB = 64 + jA;           // phase-B rows

  // --- W_hh fragments resident in VGPRs: [phase][gate][slice][ktile] ---
  bf16x8 Wf[2][3][4][4];
#pragma unroll
  for (int ph = 0; ph < 2; ++ph)
#pragma unroll
    for (int gt = 0; gt < 3; ++gt)
#pragma unroll
      for (int sl = 0; sl < 4; ++sl)
#pragma unroll
        for (int kt = 0; kt < 4; ++kt) {
          const float* rp =
              whh + (size_t)(gt * 128 + ph * 64 + sl * 16 + c) * 128 + kt * 32 + g * 8;
          float4 v0 = *reinterpret_cast<const float4*>(rp);
          float4 v1 = *reinterpret_cast<const float4*>(rp + 4);
          bf16x8 f;
          f[0] = (short)f2bf(v0.x); f[1] = (short)f2bf(v0.y);
          f[2] = (short)f2bf(v0.z); f[3] = (short)f2bf(v0.w);
          f[4] = (short)f2bf(v1.x); f[5] = (short)f2bf(v1.y);
          f[6] = (short)f2bf(v1.z); f[7] = (short)f2bf(v1.w);
          Wf[ph][gt][sl][kt] = f;
        }

  // --- n-gate hidden bias (r,z folded into xbias by k0) ---
  float bh2A[4], bh2B[4];
#pragma unroll
  for (int r = 0; r < 4; ++r) {
    bh2A[r] = bhh[256 + jA + r];
    bh2B[r] = bhh[256 + jB + r];
  }

  const int len = seqlen[b];
  float hA[4], hB[4], accA[4], accB[4];
#pragma unroll
  for (int r = 0; r < 4; ++r) {
    hA[r] = hidden[(size_t)(dir * 64 + b) * 128 + jA + r];
    hB[r] = hidden[(size_t)(dir * 64 + b) * 128 + jB + r];
    accA[r] = 0.f; accB[r] = 0.f;
  }
  // init hL (writers cover all 128 rows exactly once)
  {
    ushort4 pv;
    if (c < 4) {
      pv.x = f2bf(hA[0]); pv.y = f2bf(hA[1]); pv.z = f2bf(hA[2]); pv.w = f2bf(hA[3]);
      *reinterpret_cast<ushort4*>(&hL[jA]) = pv;
    } else if (c < 8) {
      pv.x = f2bf(hB[0]); pv.y = f2bf(hB[1]); pv.z = f2bf(hB[2]); pv.w = f2bf(hB[3]);
      *reinterpret_cast<ushort4*>(&hL[jB]) = pv;
    }
  }
  asm volatile("s_waitcnt lgkmcnt(0)" ::: "memory");

  // --- x prefetch for t=0 ---
  const unsigned short* xpb = xp + (size_t)b * (1024 * 768) + dir * 384;
  int row = dir ? (len - 1) : 0;
  ushort4 xAn[3], xBn[3];
#pragma unroll
  for (int gt = 0; gt < 3; ++gt) {
    xAn[gt] = *reinterpret_cast<const ushort4*>(xpb + (size_t)row * 768 + gt * 128 + jA);
    xBn[gt] = *reinterpret_cast<const ushort4*>(xpb + (size_t)row * 768 + gt * 128 + jB);
  }

  const f32x4 ZZ = (f32x4){0.f, 0.f, 0.f, 0.f};

  for (int t = 0; t < len; ++t) {
    // consume prefetched x; issue next step's loads (slack = full step)
    ushort4 xA[3], xB[3];
#pragma unroll
    for (int gt = 0; gt < 3; ++gt) { xA[gt] = xAn[gt]; xB[gt] = xBn[gt]; }
    {
      const int sel = (t + 1 < len) ? 1 : 0;
      row += dir ? -sel : sel;
#pragma unroll
      for (int gt = 0; gt < 3; ++gt) {
        xAn[gt] = *reinterpret_cast<const ushort4*>(xpb + (size_t)row * 768 + gt * 128 + jA);
        xBn[gt] = *reinterpret_cast<const ushort4*>(xpb + (size_t)row * 768 + gt * 128 + jB);
      }
    }

    // B-frags: h broadcast (same 16B for all lanes in a k-subgroup)
    bf16x8 Bf[4];
#pragma unroll
    for (int kt = 0; kt < 4; ++kt)
      Bf[kt] = *reinterpret_cast<const bf16x8*>(&hL[kt * 32 + g * 8]);

#pragma unroll
    for (int ph = 0; ph < 2; ++ph) {
      // 48 MFMA; per-gate select collapses C live range to 4 regs
      f32x4 Cs[3];
#pragma unroll
      for (int gt = 0; gt < 3; ++gt) {
        f32x4 C0 = ZZ, C1 = ZZ, C2 = ZZ, C3 = ZZ;
#pragma unroll
        for (int kt = 0; kt < 4; ++kt) {
          C0 = __builtin_amdgcn_mfma_f32_16x16x32_bf16(Wf[ph][gt][0][kt], Bf[kt], C0, 0, 0, 0);
          C1 = __builtin_amdgcn_mfma_f32_16x16x32_bf16(Wf[ph][gt][1][kt], Bf[kt], C1, 0, 0, 0);
          C2 = __builtin_amdgcn_mfma_f32_16x16x32_bf16(Wf[ph][gt][2][kt], Bf[kt], C2, 0, 0, 0);
          C3 = __builtin_amdgcn_mfma_f32_16x16x32_bf16(Wf[ph][gt][3][kt], Bf[kt], C3, 0, 0, 0);
        }
        Cs[gt] = sel4(C0, C1, C2, C3, c);
      }

      // register-local gate combine for this lane's 4 rows
      float* hh  = ph ? hB : hA;
      float* ac  = ph ? accB : accA;
      float* bb2 = ph ? bh2B : bh2A;
      ushort4* xx = ph ? xB : xA;
      ushort4 pv;
      unsigned short* pvp = reinterpret_cast<unsigned short*>(&pv);
#pragma unroll
      for (int r = 0; r < 4; ++r) {
        const float xr = bf2f(((const unsigned short*)&xx[0])[r]);
        const float xz = bf2f(((const unsigned short*)&xx[1])[r]);
        const float xn = bf2f(((const unsigned short*)&xx[2])[r]);
        const float rr = 1.f / (1.f + __expf(-(xr + Cs[0][r])));
        const float zz = 1.f / (1.f + __expf(-(xz + Cs[1][r])));
        const float na = xn + rr * (Cs[2][r] + bb2[r]);
        const float e2 = __expf(2.f * na);
        const float nn = (e2 - 1.f) / (e2 + 1.f);
        const float hn = (1.f - zz) * nn + zz * hh[r];
        ac[r] += hn;
        hh[r] = hn;
        pvp[r] = f2bf(hn);
      }
      // publish h' rows for this phase (16 writer lanes each)
      if (ph == 0) {
        if (c < 4) *reinterpret_cast<ushort4*>(&hL[jA]) = pv;
      } else {
        if (c >= 4 && c < 8) *reinterpret_cast<ushort4*>(&hL[jB]) = pv;
      }
    }
    // order h' writes before next iteration's B-frag reads (same wave, no barrier)
    asm volatile("s_waitcnt lgkmcnt(0)" ::: "memory");
  }

  // --- masked mean ---
  const float inv = 1.f / (float)len;
  if (c < 4) {
    float4 o = make_float4(accA[0] * inv, accA[1] * inv, accA[2] * inv, accA[3] * inv);
    *reinterpret_cast<float4*>(&mot[(size_t)b * 256 + dir * 128 + jA]) = o;
  } else if (c < 8) {
    float4 o = make_float4(accB[0] * inv, accB[1] * inv, accB[2] * inv, accB[3] * inv);
    *reinterpret_cast<float4*>(&mot[(size_t)b * 256 + dir * 128 + jB]) = o;
  }
}

// ---------------------------------------------------------------------------
// K3: out[b] = sigmoid(dot(mot[b], lin_w) + lin_b)
__global__ void k3_final(const float* __restrict__ mot, const float* __restrict__ lin_w,
                         const float* __restrict__ lin_b, float* __restrict__ out) {
  int tid = threadIdx.x;
  int b = tid >> 2, part = tid & 3;
  float s = 0.f;
  for (int i = 0; i < 64; ++i) s += mot[b * 256 + part * 64 + i] * lin_w[part * 64 + i];
  s += __shfl_xor(s, 1);
  s += __shfl_xor(s, 2);
  if (part == 0) out[b] = 1.f / (1.f + __expf(-(s + lin_b[0])));
}

// ---------------------------------------------------------------------------
extern "C" void kernel_launch(void* const* d_in, const int* in_sizes, int n_in,
                              void* d_out, int out_size, void* d_ws, size_t ws_size,
                              hipStream_t stream) {
  const int*   ipts    = (const int*)d_in[0];
  const int*   seqlen  = (const int*)d_in[1];
  const float* hidden  = (const float*)d_in[2];
  const float* emb     = (const float*)d_in[3];
  const float* conv_w  = (const float*)d_in[4];
  const float* conv_b  = (const float*)d_in[5];
  const float* w_ih_f  = (const float*)d_in[6];
  const float* w_hh_f  = (const float*)d_in[7];
  const float* b_ih_f  = (const float*)d_in[8];
  const float* b_hh_f  = (const float*)d_in[9];
  const float* w_ih_b  = (const float*)d_in[10];
  const float* w_hh_b  = (const float*)d_in[11];
  const float* b_ih_b  = (const float*)d_in[12];
  const float* b_hh_b  = (const float*)d_in[13];
  const float* lin_w   = (const float*)d_in[14];
  const float* lin_b   = (const float*)d_in[15];

  char* ws = (char*)d_ws;
  unsigned short* CWb = (unsigned short*)(ws);           // 294,912 B
  float* xbias = (float*)(ws + 294912);                  // 3,072 B
  float* mot   = (float*)(ws + 298240);                  // 65,536 B
  unsigned short* xp = (unsigned short*)(ws + 1048576);  // 100,663,296 B (bf16)
  float* out = (float*)d_out;

  hipLaunchKernelGGL(k0_fuse, dim3(576), dim3(256), 0, stream,
                     conv_w, conv_b, w_ih_f, b_ih_f, w_ih_b, b_ih_b, b_hh_f, b_hh_b,
                     CWb, xbias);
  hipLaunchKernelGGL(k1_gemm, dim3(3072), dim3(256), 0, stream,
                     ipts, emb, CWb, xbias, xp);
  hipLaunchKernelGGL(k2_scan, dim3(128), dim3(64), 0, stream,
                     seqlen, hidden, w_hh_f, b_hh_f, w_hh_b, b_hh_b, xp, mot);
  hipLaunchKernelGGL(k3_final, dim3(1), dim3(256), 0, stream, mot, lin_w, lin_b, out);
}

// Round 8
// 791.261 us; speedup vs baseline: 3.4461x; 3.4461x over previous
//
#include <hip/hip_runtime.h>

// V=50000, E=64, B=64, T=1024, F=128, H=128, WIN=3, PAD=1

typedef __attribute__((ext_vector_type(8))) unsigned short ushort8;
typedef __attribute__((ext_vector_type(8))) short bf16x8;
typedef __attribute__((ext_vector_type(4))) float f32x4;

__device__ __forceinline__ unsigned short f2bf(float f) {
  unsigned int u = __float_as_uint(f);
  u += 0x7fffu + ((u >> 16) & 1u);   // RNE
  return (unsigned short)(u >> 16);
}
__device__ __forceinline__ float bf2f(unsigned short us) {
  return __uint_as_float(((unsigned int)us) << 16);
}
#if __has_builtin(__builtin_amdgcn_sdot4)
#define SDOT4(a, b, c) __builtin_amdgcn_sdot4((int)(a), (int)(b), (c), false)
#else
__device__ __forceinline__ int sdot4_sw(int a, int b, int c) {
#pragma unroll
  for (int i = 0; i < 4; ++i)
    c += ((a << (24 - 8 * i)) >> 24) * ((b << (24 - 8 * i)) >> 24);
  return c;
}
#define SDOT4(a, b, c) sdot4_sw((int)(a), (int)(b), (c))
#endif

// ---------------------------------------------------------------------------
// K0: CWb[g][k] = bf16( sum_f Wih[g][f]*conv_w[f][k] );
//     xbias[g] = b_ih[g] + Wih[g]·conv_b (+ b_hh folded for r,z gates).
__global__ void k0_fuse(const float* __restrict__ conv_w, const float* __restrict__ conv_b,
                        const float* __restrict__ w_ih_f, const float* __restrict__ b_ih_f,
                        const float* __restrict__ w_ih_b, const float* __restrict__ b_ih_b,
                        const float* __restrict__ b_hh_f, const float* __restrict__ b_hh_b,
                        unsigned short* __restrict__ CWb, float* __restrict__ xbias) {
  int flat = blockIdx.x * 256 + threadIdx.x;
  if (flat >= 768 * 192) return;
  int g = flat / 192, k = flat % 192;
  const float* wih = (g < 384) ? w_ih_f : w_ih_b;
  int gg = (g < 384) ? g : g - 384;
  float acc = 0.f;
  for (int f = 0; f < 128; ++f) acc += wih[gg * 128 + f] * conv_w[f * 192 + k];
  CWb[g * 192 + k] = f2bf(acc);
  if (k == 0) {
    const float* bih = (g < 384) ? b_ih_f : b_ih_b;
    const float* bhh = (g < 384) ? b_hh_f : b_hh_b;
    float bb = bih[gg];
    if (gg < 256) bb += bhh[gg];   // fold hidden bias for r,z
    for (int f = 0; f < 128; ++f) bb += wih[gg * 128 + f] * conv_b[f];
    xbias[g] = bb;
  }
}

// ---------------------------------------------------------------------------
// K0b: per-row i8 quantization of W_hh (both dirs): row R = dir*384+gate*128+j.
//      32 threads per row, thread = one dword (4 k). ws[R] = absmax/(127*127).
__global__ void k0b_quant(const float* __restrict__ w_hh_f, const float* __restrict__ w_hh_b,
                          unsigned int* __restrict__ Wq8, float* __restrict__ ws) {
  int tid = blockIdx.x * 256 + threadIdx.x;
  int R = tid >> 5, dw = tid & 31;
  if (R >= 768) return;
  int dir = R / 384, rr = R - dir * 384;
  const float* w = (dir ? w_hh_b : w_hh_f) + (size_t)rr * 128 + dw * 4;
  float4 v = *reinterpret_cast<const float4*>(w);
  float am = fmaxf(fmaxf(fabsf(v.x), fabsf(v.y)), fmaxf(fabsf(v.z), fabsf(v.w)));
#pragma unroll
  for (int m = 1; m < 32; m <<= 1) am = fmaxf(am, __shfl_xor(am, m));
  float inv = (am > 0.f) ? 127.f / am : 0.f;
  int q0 = (int)rintf(v.x * inv), q1 = (int)rintf(v.y * inv);
  int q2 = (int)rintf(v.z * inv), q3 = (int)rintf(v.w * inv);
  unsigned int pk = (q0 & 255) | ((q1 & 255) << 8) | ((q2 & 255) << 16) | ((q3 & 255) << 24);
  Wq8[R * 32 + dw] = pk;
  if (dw == 0) ws[R] = am / 16129.f;
}

// ---------------------------------------------------------------------------
// K1: xp[b][t][g] = bf16( xbias[g] + sum_k A[t][k]*CW[g][k] ) via MFMA bf16.
__global__ __launch_bounds__(256) void k1_gemm(const int* __restrict__ ipts,
                                               const float* __restrict__ emb,
                                               const unsigned short* __restrict__ CWb,
                                               const float* __restrict__ xbias,
                                               unsigned short* __restrict__ xp) {
  __shared__ __align__(16) unsigned short xs[130][72];
  __shared__ __align__(16) unsigned short wsb[128][200];
  const int bid = blockIdx.x;
  const int gb = bid % 6, tb = bid / 6;
  const int b = tb >> 3, t0 = (tb & 7) << 7, g0 = gb << 7;
  const int tid = threadIdx.x;

  for (int c = tid; c < 130 * 16; c += 256) {
    int row = c >> 4, cc = c & 15;
    int t = t0 - 1 + row;
    float4 v = make_float4(0.f, 0.f, 0.f, 0.f);
    if (t >= 0 && t < 1024) {
      int tok = ipts[b * 1024 + t];
      v = *reinterpret_cast<const float4*>(emb + (size_t)tok * 64 + cc * 4);
    }
    ushort4 pv;
    pv.x = f2bf(v.x); pv.y = f2bf(v.y); pv.z = f2bf(v.z); pv.w = f2bf(v.w);
    *reinterpret_cast<ushort4*>(&xs[row][cc * 4]) = pv;
  }
  for (int c = tid; c < 128 * 24; c += 256) {
    int g = c / 24, cc = c % 24;
    *reinterpret_cast<ushort8*>(&wsb[g][cc * 8]) =
        *reinterpret_cast<const ushort8*>(CWb + (size_t)(g0 + g) * 192 + cc * 8);
  }
  __syncthreads();

  const int lane = tid & 63, wid = tid >> 6;
  const int wy = wid >> 1, wx = wid & 1;
  const int ln15 = lane & 15, lhi = lane >> 4;

  f32x4 acc[4][4];
#pragma unroll
  for (int i = 0; i < 4; ++i)
#pragma unroll
    for (int j = 0; j < 4; ++j) acc[i][j] = (f32x4){0.f, 0.f, 0.f, 0.f};

#pragma unroll
  for (int kk = 0; kk < 6; ++kk) {
    const int w = kk >> 1;
    const int e0 = (kk & 1) * 32 + lhi * 8;
    const int k0 = kk * 32 + lhi * 8;
    bf16x8 a[4], bb[4];
#pragma unroll
    for (int i = 0; i < 4; ++i)
      a[i] = *reinterpret_cast<const bf16x8*>(&xs[wy * 64 + i * 16 + ln15 + w][e0]);
#pragma unroll
    for (int j = 0; j < 4; ++j)
      bb[j] = *reinterpret_cast<const bf16x8*>(&wsb[wx * 64 + j * 16 + ln15][k0]);
#pragma unroll
    for (int i = 0; i < 4; ++i)
#pragma unroll
      for (int j = 0; j < 4; ++j)
        acc[i][j] = __builtin_amdgcn_mfma_f32_16x16x32_bf16(a[i], bb[j], acc[i][j], 0, 0, 0);
  }

  float bias[4];
#pragma unroll
  for (int j = 0; j < 4; ++j) bias[j] = xbias[g0 + wx * 64 + j * 16 + ln15];

  unsigned short* outp = xp + (size_t)(b * 1024 + t0 + wy * 64) * 768 + g0 + wx * 64;
#pragma unroll
  for (int i = 0; i < 4; ++i)
#pragma unroll
    for (int r = 0; r < 4; ++r) {
      int m = i * 16 + lhi * 4 + r;
#pragma unroll
      for (int j = 0; j < 4; ++j)
        outp[(size_t)m * 768 + j * 16 + ln15] = f2bf(acc[i][j][r] + bias[j]);
    }
}

// ---------------------------------------------------------------------------
// K2: GRU scan — ONE WAVE per (batch, direction), 128 single-wave blocks,
//     ZERO barriers, i8 dot4 matvec. Lane L owns rows j0=2L, j0+1 for all 3
//     gates: W_hh i8 resident in 192 VGPRs (6 rows x 32 dwords). h kept i8
//     (|h|<1 -> fixed 127 scale) in 256B double-buffered wave-private LDS:
//     8 ds_read_b128 broadcast/step, 192 v_dot4_i32_i8, 1 ds_write_b16.
//     Recurrence state h stays f32 in registers (only dot input quantized).
//     x-gates: 3 global dword loads, depth-1 prefetch (xp L3-resident).
//     len is wave-uniform (whole wave = one chain) -> loop runs exactly len.
__global__ __launch_bounds__(64, 1) void k2_scan(
    const int* __restrict__ seqlen, const float* __restrict__ hidden,
    const float* __restrict__ b_hh_f, const float* __restrict__ b_hh_b,
    const unsigned int* __restrict__ Wq8, const float* __restrict__ ws,
    const unsigned short* __restrict__ xp, float* __restrict__ mot) {
  __shared__ __align__(16) unsigned int hbw[2][32];   // h as i8, double-buffered
  const int L = threadIdx.x;
  const int b = blockIdx.x & 63, dir = blockIdx.x >> 6;
  const int j0 = 2 * L;
  const float* bhh = dir ? b_hh_b : b_hh_f;

  // --- W_hh i8 fragments resident: Wq[gate][jj][8 dwordx4] = 192 VGPR ---
  uint4 Wq[3][2][8];
  float sc[3][2];
#pragma unroll
  for (int g = 0; g < 3; ++g)
#pragma unroll
    for (int jj = 0; jj < 2; ++jj) {
      const int R = dir * 384 + g * 128 + j0 + jj;
      const uint4* rp = reinterpret_cast<const uint4*>(Wq8 + (size_t)R * 32);
#pragma unroll
      for (int c = 0; c < 8; ++c) Wq[g][jj][c] = rp[c];
      sc[g][jj] = ws[R];
    }
  const float bh2a = bhh[256 + j0], bh2b = bhh[256 + j0 + 1];

  const int len = seqlen[b];
  float hA = hidden[(size_t)(dir * 64 + b) * 128 + j0];
  float hB = hidden[(size_t)(dir * 64 + b) * 128 + j0 + 1];
  float accA = 0.f, accB = 0.f;
  {
    int q0 = (int)rintf(hA * 127.f), q1 = (int)rintf(hB * 127.f);
    ((unsigned short*)&hbw[0][0])[L] = (unsigned short)((q0 & 255) | ((q1 & 255) << 8));
  }

  const unsigned short* xpb = xp + (size_t)b * (1024 * 768) + dir * 384;
  int row = dir ? (len - 1) : 0;
  unsigned int xn0, xn1, xn2;
  xn0 = *reinterpret_cast<const unsigned int*>(xpb + (size_t)row * 768 + j0);
  xn1 = *reinterpret_cast<const unsigned int*>(xpb + (size_t)row * 768 + 128 + j0);
  xn2 = *reinterpret_cast<const unsigned int*>(xpb + (size_t)row * 768 + 256 + j0);

  for (int t = 0; t < len; ++t) {
    const int cur = t & 1;
    const unsigned int xc0 = xn0, xc1 = xn1, xc2 = xn2;
    {  // prefetch next step's x (consumed ~600 cyc later)
      const int sel = (t + 1 < len) ? 1 : 0;
      row += dir ? -sel : sel;
      const unsigned short* pp = xpb + (size_t)row * 768 + j0;
      xn0 = *reinterpret_cast<const unsigned int*>(pp);
      xn1 = *reinterpret_cast<const unsigned int*>(pp + 128);
      xn2 = *reinterpret_cast<const unsigned int*>(pp + 256);
    }

    // matvec: 6 accumulators, 192 sdot4 (LDS reads are wave-broadcast)
    int ar = 0, az = 0, an = 0, br = 0, bz = 0, bn = 0;
    const uint4* hp = reinterpret_cast<const uint4*>(&hbw[cur][0]);
#pragma unroll
    for (int c = 0; c < 8; ++c) {
      const uint4 hv = hp[c];
      ar = SDOT4(Wq[0][0][c].x, hv.x, ar); ar = SDOT4(Wq[0][0][c].y, hv.y, ar);
      ar = SDOT4(Wq[0][0][c].z, hv.z, ar); ar = SDOT4(Wq[0][0][c].w, hv.w, ar);
      az = SDOT4(Wq[1][0][c].x, hv.x, az); az = SDOT4(Wq[1][0][c].y, hv.y, az);
      az = SDOT4(Wq[1][0][c].z, hv.z, az); az = SDOT4(Wq[1][0][c].w, hv.w, az);
      an = SDOT4(Wq[2][0][c].x, hv.x, an); an = SDOT4(Wq[2][0][c].y, hv.y, an);
      an = SDOT4(Wq[2][0][c].z, hv.z, an); an = SDOT4(Wq[2][0][c].w, hv.w, an);
      br = SDOT4(Wq[0][1][c].x, hv.x, br); br = SDOT4(Wq[0][1][c].y, hv.y, br);
      br = SDOT4(Wq[0][1][c].z, hv.z, br); br = SDOT4(Wq[0][1][c].w, hv.w, br);
      bz = SDOT4(Wq[1][1][c].x, hv.x, bz); bz = SDOT4(Wq[1][1][c].y, hv.y, bz);
      bz = SDOT4(Wq[1][1][c].z, hv.z, bz); bz = SDOT4(Wq[1][1][c].w, hv.w, bz);
      bn = SDOT4(Wq[2][1][c].x, hv.x, bn); bn = SDOT4(Wq[2][1][c].y, hv.y, bn);
      bn = SDOT4(Wq[2][1][c].z, hv.z, bn); bn = SDOT4(Wq[2][1][c].w, hv.w, bn);
    }

    // gates (r,z biases folded into xp by k0; n-gate bias explicit)
    const float xrA = bf2f((unsigned short)(xc0 & 0xFFFF));
    const float xrB = bf2f((unsigned short)(xc0 >> 16));
    const float xzA = bf2f((unsigned short)(xc1 & 0xFFFF));
    const float xzB = bf2f((unsigned short)(xc1 >> 16));
    const float xnA = bf2f((unsigned short)(xc2 & 0xFFFF));
    const float xnB = bf2f((unsigned short)(xc2 >> 16));
    const float rA = 1.f / (1.f + __expf(-(xrA + sc[0][0] * (float)ar)));
    const float zA = 1.f / (1.f + __expf(-(xzA + sc[1][0] * (float)az)));
    const float naA = xnA + rA * (sc[2][0] * (float)an + bh2a);
    const float e2A = __expf(2.f * naA);
    const float nA = (e2A - 1.f) / (e2A + 1.f);
    hA = (1.f - zA) * nA + zA * hA;
    accA += hA;
    const float rB = 1.f / (1.f + __expf(-(xrB + sc[0][1] * (float)br)));
    const float zB = 1.f / (1.f + __expf(-(xzB + sc[1][1] * (float)bz)));
    const float naB = xnB + rB * (sc[2][1] * (float)bn + bh2b);
    const float e2B = __expf(2.f * naB);
    const float nB = (e2B - 1.f) / (e2B + 1.f);
    hB = (1.f - zB) * nB + zB * hB;
    accB += hB;

    // publish h(t+1) as i8 into the other buffer (same-wave DS ordering)
    int qa = (int)rintf(hA * 127.f), qb = (int)rintf(hB * 127.f);
    ((unsigned short*)&hbw[cur ^ 1][0])[L] = (unsigned short)((qa & 255) | ((qb & 255) << 8));
  }

  const float inv = 1.f / (float)len;
  *reinterpret_cast<float2*>(&mot[(size_t)b * 256 + dir * 128 + j0]) =
      make_float2(accA * inv, accB * inv);
}

// ---------------------------------------------------------------------------
// K3: out[b] = sigmoid(dot(mot[b], lin_w) + lin_b)
__global__ void k3_final(const float* __restrict__ mot, const float* __restrict__ lin_w,
                         const float* __restrict__ lin_b, float* __restrict__ out) {
  int tid = threadIdx.x;
  int b = tid >> 2, part = tid & 3;
  float s = 0.f;
  for (int i = 0; i < 64; ++i) s += mot[b * 256 + part * 64 + i] * lin_w[part * 64 + i];
  s += __shfl_xor(s, 1);
  s += __shfl_xor(s, 2);
  if (part == 0) out[b] = 1.f / (1.f + __expf(-(s + lin_b[0])));
}

// ---------------------------------------------------------------------------
extern "C" void kernel_launch(void* const* d_in, const int* in_sizes, int n_in,
                              void* d_out, int out_size, void* d_ws, size_t ws_size,
                              hipStream_t stream) {
  const int*   ipts    = (const int*)d_in[0];
  const int*   seqlen  = (const int*)d_in[1];
  const float* hidden  = (const float*)d_in[2];
  const float* emb     = (const float*)d_in[3];
  const float* conv_w  = (const float*)d_in[4];
  const float* conv_b  = (const float*)d_in[5];
  const float* w_ih_f  = (const float*)d_in[6];
  const float* w_hh_f  = (const float*)d_in[7];
  const float* b_ih_f  = (const float*)d_in[8];
  const float* b_hh_f  = (const float*)d_in[9];
  const float* w_ih_b  = (const float*)d_in[10];
  const float* w_hh_b  = (const float*)d_in[11];
  const float* b_ih_b  = (const float*)d_in[12];
  const float* b_hh_b  = (const float*)d_in[13];
  const float* lin_w   = (const float*)d_in[14];
  const float* lin_b   = (const float*)d_in[15];

  char* ws_ = (char*)d_ws;
  unsigned short* CWb = (unsigned short*)(ws_);            // 294,912 B
  float* xbias = (float*)(ws_ + 294912);                   // 3,072 B
  float* mot   = (float*)(ws_ + 298240);                   // 65,536 B
  unsigned int* Wq8 = (unsigned int*)(ws_ + 363776);       // 98,304 B (768 rows x 128 i8)
  float* wsc   = (float*)(ws_ + 462080);                   // 3,072 B
  unsigned short* xp = (unsigned short*)(ws_ + 1048576);   // 100,663,296 B (bf16)
  float* out = (float*)d_out;

  hipLaunchKernelGGL(k0_fuse, dim3(576), dim3(256), 0, stream,
                     conv_w, conv_b, w_ih_f, b_ih_f, w_ih_b, b_ih_b, b_hh_f, b_hh_b,
                     CWb, xbias);
  hipLaunchKernelGGL(k0b_quant, dim3(96), dim3(256), 0, stream,
                     w_hh_f, w_hh_b, Wq8, wsc);
  hipLaunchKernelGGL(k1_gemm, dim3(3072), dim3(256), 0, stream,
                     ipts, emb, CWb, xbias, xp);
  hipLaunchKernelGGL(k2_scan, dim3(128), dim3(64), 0, stream,
                     seqlen, hidden, b_hh_f, b_hh_b, Wq8, wsc, xp, mot);
  hipLaunchKernelGGL(k3_final, dim3(1), dim3(256), 0, stream, mot, lin_w, lin_b, out);
}

// Round 9
// 760.344 us; speedup vs baseline: 3.5863x; 1.0407x over previous
//
#include <hip/hip_runtime.h>

// V=50000, E=64, B=64, T=1024, F=128, H=128, WIN=3, PAD=1

typedef __attribute__((ext_vector_type(8))) unsigned short ushort8;
typedef __attribute__((ext_vector_type(8))) short bf16x8;
typedef __attribute__((ext_vector_type(4))) float f32x4;

__device__ __forceinline__ unsigned short f2bf(float f) {
  unsigned int u = __float_as_uint(f);
  u += 0x7fffu + ((u >> 16) & 1u);   // RNE
  return (unsigned short)(u >> 16);
}
__device__ __forceinline__ float bf2f(unsigned short us) {
  return __uint_as_float(((unsigned int)us) << 16);
}
#if __has_builtin(__builtin_amdgcn_sdot4)
#define SDOT4(a, b, c) __builtin_amdgcn_sdot4((int)(a), (int)(b), (c), false)
#else
__device__ __forceinline__ int sdot4_sw(int a, int b, int c) {
#pragma unroll
  for (int i = 0; i < 4; ++i)
    c += ((a << (24 - 8 * i)) >> 24) * ((b << (24 - 8 * i)) >> 24);
  return c;
}
#define SDOT4(a, b, c) sdot4_sw((int)(a), (int)(b), (c))
#endif

// ---------------------------------------------------------------------------
// K0: CWb[g][k] = bf16( sum_f Wih[g][f]*conv_w[f][k] );
//     xbias[g] = b_ih[g] + Wih[g]·conv_b (+ b_hh folded for r,z gates).
__global__ void k0_fuse(const float* __restrict__ conv_w, const float* __restrict__ conv_b,
                        const float* __restrict__ w_ih_f, const float* __restrict__ b_ih_f,
                        const float* __restrict__ w_ih_b, const float* __restrict__ b_ih_b,
                        const float* __restrict__ b_hh_f, const float* __restrict__ b_hh_b,
                        unsigned short* __restrict__ CWb, float* __restrict__ xbias) {
  int flat = blockIdx.x * 256 + threadIdx.x;
  if (flat >= 768 * 192) return;
  int g = flat / 192, k = flat % 192;
  const float* wih = (g < 384) ? w_ih_f : w_ih_b;
  int gg = (g < 384) ? g : g - 384;
  float acc = 0.f;
  for (int f = 0; f < 128; ++f) acc += wih[gg * 128 + f] * conv_w[f * 192 + k];
  CWb[g * 192 + k] = f2bf(acc);
  if (k == 0) {
    const float* bih = (g < 384) ? b_ih_f : b_ih_b;
    const float* bhh = (g < 384) ? b_hh_f : b_hh_b;
    float bb = bih[gg];
    if (gg < 256) bb += bhh[gg];   // fold hidden bias for r,z
    for (int f = 0; f < 128; ++f) bb += wih[gg * 128 + f] * conv_b[f];
    xbias[g] = bb;
  }
}

// ---------------------------------------------------------------------------
// K0b: per-row i8 quantization of W_hh (both dirs): row R = dir*384+gate*128+j.
__global__ void k0b_quant(const float* __restrict__ w_hh_f, const float* __restrict__ w_hh_b,
                          unsigned int* __restrict__ Wq8, float* __restrict__ ws) {
  int tid = blockIdx.x * 256 + threadIdx.x;
  int R = tid >> 5, dw = tid & 31;
  if (R >= 768) return;
  int dir = R / 384, rr = R - dir * 384;
  const float* w = (dir ? w_hh_b : w_hh_f) + (size_t)rr * 128 + dw * 4;
  float4 v = *reinterpret_cast<const float4*>(w);
  float am = fmaxf(fmaxf(fabsf(v.x), fabsf(v.y)), fmaxf(fabsf(v.z), fabsf(v.w)));
#pragma unroll
  for (int m = 1; m < 32; m <<= 1) am = fmaxf(am, __shfl_xor(am, m));
  float inv = (am > 0.f) ? 127.f / am : 0.f;
  int q0 = (int)rintf(v.x * inv), q1 = (int)rintf(v.y * inv);
  int q2 = (int)rintf(v.z * inv), q3 = (int)rintf(v.w * inv);
  unsigned int pk = (q0 & 255) | ((q1 & 255) << 8) | ((q2 & 255) << 16) | ((q3 & 255) << 24);
  Wq8[R * 32 + dw] = pk;
  if (dw == 0) ws[R] = am / 16129.f;
}

// ---------------------------------------------------------------------------
// K1: xp[b][t][g] = bf16( xbias[g] + sum_k A[t][k]*CW[g][k] ) via MFMA bf16.
__global__ __launch_bounds__(256) void k1_gemm(const int* __restrict__ ipts,
                                               const float* __restrict__ emb,
                                               const unsigned short* __restrict__ CWb,
                                               const float* __restrict__ xbias,
                                               unsigned short* __restrict__ xp) {
  __shared__ __align__(16) unsigned short xs[130][72];
  __shared__ __align__(16) unsigned short wsb[128][200];
  const int bid = blockIdx.x;
  const int gb = bid % 6, tb = bid / 6;
  const int b = tb >> 3, t0 = (tb & 7) << 7, g0 = gb << 7;
  const int tid = threadIdx.x;

  for (int c = tid; c < 130 * 16; c += 256) {
    int row = c >> 4, cc = c & 15;
    int t = t0 - 1 + row;
    float4 v = make_float4(0.f, 0.f, 0.f, 0.f);
    if (t >= 0 && t < 1024) {
      int tok = ipts[b * 1024 + t];
      v = *reinterpret_cast<const float4*>(emb + (size_t)tok * 64 + cc * 4);
    }
    ushort4 pv;
    pv.x = f2bf(v.x); pv.y = f2bf(v.y); pv.z = f2bf(v.z); pv.w = f2bf(v.w);
    *reinterpret_cast<ushort4*>(&xs[row][cc * 4]) = pv;
  }
  for (int c = tid; c < 128 * 24; c += 256) {
    int g = c / 24, cc = c % 24;
    *reinterpret_cast<ushort8*>(&wsb[g][cc * 8]) =
        *reinterpret_cast<const ushort8*>(CWb + (size_t)(g0 + g) * 192 + cc * 8);
  }
  __syncthreads();

  const int lane = tid & 63, wid = tid >> 6;
  const int wy = wid >> 1, wx = wid & 1;
  const int ln15 = lane & 15, lhi = lane >> 4;

  f32x4 acc[4][4];
#pragma unroll
  for (int i = 0; i < 4; ++i)
#pragma unroll
    for (int j = 0; j < 4; ++j) acc[i][j] = (f32x4){0.f, 0.f, 0.f, 0.f};

#pragma unroll
  for (int kk = 0; kk < 6; ++kk) {
    const int w = kk >> 1;
    const int e0 = (kk & 1) * 32 + lhi * 8;
    const int k0 = kk * 32 + lhi * 8;
    bf16x8 a[4], bb[4];
#pragma unroll
    for (int i = 0; i < 4; ++i)
      a[i] = *reinterpret_cast<const bf16x8*>(&xs[wy * 64 + i * 16 + ln15 + w][e0]);
#pragma unroll
    for (int j = 0; j < 4; ++j)
      bb[j] = *reinterpret_cast<const bf16x8*>(&wsb[wx * 64 + j * 16 + ln15][k0]);
#pragma unroll
    for (int i = 0; i < 4; ++i)
#pragma unroll
      for (int j = 0; j < 4; ++j)
        acc[i][j] = __builtin_amdgcn_mfma_f32_16x16x32_bf16(a[i], bb[j], acc[i][j], 0, 0, 0);
  }

  float bias[4];
#pragma unroll
  for (int j = 0; j < 4; ++j) bias[j] = xbias[g0 + wx * 64 + j * 16 + ln15];

  unsigned short* outp = xp + (size_t)(b * 1024 + t0 + wy * 64) * 768 + g0 + wx * 64;
#pragma unroll
  for (int i = 0; i < 4; ++i)
#pragma unroll
    for (int r = 0; r < 4; ++r) {
      int m = i * 16 + lhi * 4 + r;
#pragma unroll
      for (int j = 0; j < 4; ++j)
        outp[(size_t)m * 768 + j * 16 + ln15] = f2bf(acc[i][j][r] + bias[j]);
    }
}

// ---------------------------------------------------------------------------
// K2: GRU scan — ONE WAVE per (batch, direction), zero barriers, i8 sdot4.
//     W_hh i8 loaded via VOLATILE ASM dwordx4 (cannot be rematerialized ->
//     forced VGPR-resident, 192 regs). x-prefetch depth 2 via asm loads with
//     counted s_waitcnt vmcnt(3)+sched_barrier before consume (guide T4/#18):
//     no compiler vm loads remain in the loop, so nothing drains the queue.
//     Loop unrolled 2x so h double-buffer indices are compile-time constants.
__global__ __launch_bounds__(64, 1) void k2_scan(
    const int* __restrict__ seqlen, const float* __restrict__ hidden,
    const float* __restrict__ b_hh_f, const float* __restrict__ b_hh_b,
    const unsigned int* __restrict__ Wq8, const float* __restrict__ ws,
    const unsigned short* __restrict__ xp, float* __restrict__ mot) {
  __shared__ __align__(16) unsigned int hbw[2][32];   // h as i8, double-buffered
  const int L = threadIdx.x;
  const int b = blockIdx.x & 63, dir = blockIdx.x >> 6;
  const int j0 = 2 * L;
  const float* bhh = dir ? b_hh_b : b_hh_f;

  // --- W_hh i8: 48 x dwordx4 via volatile asm -> forced resident (192 VGPR) ---
  uint4 Wq[3][2][8];
#pragma unroll
  for (int g = 0; g < 3; ++g)
#pragma unroll
    for (int jj = 0; jj < 2; ++jj) {
      const uint4* rp =
          reinterpret_cast<const uint4*>(Wq8 + (size_t)(dir * 384 + g * 128 + j0 + jj) * 32);
#pragma unroll
      for (int c = 0; c < 8; ++c)
        asm volatile("global_load_dwordx4 %0, %1, off"
                     : "=v"(Wq[g][jj][c]) : "v"(rp + c) : "memory");
    }

  float sc[3][2];
#pragma unroll
  for (int g = 0; g < 3; ++g)
#pragma unroll
    for (int jj = 0; jj < 2; ++jj) sc[g][jj] = ws[dir * 384 + g * 128 + j0 + jj];
  const float bh2a = bhh[256 + j0], bh2b = bhh[256 + j0 + 1];

  const int len = seqlen[b];
  float hA = hidden[(size_t)(dir * 64 + b) * 128 + j0];
  float hB = hidden[(size_t)(dir * 64 + b) * 128 + j0 + 1];
  float accA = 0.f, accB = 0.f;
  {
    int q0 = (int)rintf(hA * 127.f), q1 = (int)rintf(hB * 127.f);
    ((unsigned short*)&hbw[0][0])[L] = (unsigned short)((q0 & 255) | ((q1 & 255) << 8));
  }

  // drain ALL prologue vm loads (W asm loads + normal ones) before the ring starts
  asm volatile("s_waitcnt vmcnt(0)" ::: "memory");
  __builtin_amdgcn_sched_barrier(0);

  // --- x-prefetch ring, depth 2: slot A = even t, slot B = odd t ---
  const unsigned short* xpb = xp + (size_t)b * (1024 * 768) + dir * 384 + j0;
  unsigned int xa0, xa1, xa2, xb0, xb1, xb2;
  int row2;   // row to issue next (for step t+2 at iteration t)
  {
    const int r0 = dir ? (len - 1) : 0;
    const int r1 = dir ? (len - 2) : 1;            // len >= 256
    const unsigned short* p0 = xpb + (size_t)r0 * 768;
    const unsigned short* p1 = xpb + (size_t)r1 * 768;
    asm volatile("global_load_dword %0, %1, off"            : "=v"(xa0) : "v"(p0) : "memory");
    asm volatile("global_load_dword %0, %1, off offset:256" : "=v"(xa1) : "v"(p0) : "memory");
    asm volatile("global_load_dword %0, %1, off offset:512" : "=v"(xa2) : "v"(p0) : "memory");
    asm volatile("global_load_dword %0, %1, off"            : "=v"(xb0) : "v"(p1) : "memory");
    asm volatile("global_load_dword %0, %1, off offset:256" : "=v"(xb1) : "v"(p1) : "memory");
    asm volatile("global_load_dword %0, %1, off offset:512" : "=v"(xb2) : "v"(p1) : "memory");
    row2 = dir ? (len - 3 >= 0 ? len - 3 : 0) : (2 < len ? 2 : len - 1);
  }

#define K2_STEP(T_, CUR_, X0_, X1_, X2_)                                              \
  {                                                                                   \
    asm volatile("s_waitcnt vmcnt(3)" ::: "memory");                                  \
    __builtin_amdgcn_sched_barrier(0);                                                \
    const float xrA = bf2f((unsigned short)((X0_) & 0xFFFF));                         \
    const float xrB = bf2f((unsigned short)((X0_) >> 16));                            \
    const float xzA = bf2f((unsigned short)((X1_) & 0xFFFF));                         \
    const float xzB = bf2f((unsigned short)((X1_) >> 16));                            \
    const float xnA = bf2f((unsigned short)((X2_) & 0xFFFF));                         \
    const float xnB = bf2f((unsigned short)((X2_) >> 16));                            \
    {                                                                                 \
      const unsigned short* pp = xpb + (size_t)row2 * 768;                            \
      asm volatile("global_load_dword %0, %1, off"            : "=v"(X0_) : "v"(pp) : "memory"); \
      asm volatile("global_load_dword %0, %1, off offset:256" : "=v"(X1_) : "v"(pp) : "memory"); \
      asm volatile("global_load_dword %0, %1, off offset:512" : "=v"(X2_) : "v"(pp) : "memory"); \
      row2 = dir ? (row2 > 0 ? row2 - 1 : 0) : (row2 + 1 < len ? row2 + 1 : len - 1); \
    }                                                                                 \
    int ar = 0, az = 0, an = 0, br = 0, bz = 0, bn = 0;                               \
    const uint4* hp = reinterpret_cast<const uint4*>(&hbw[CUR_][0]);                  \
    _Pragma("unroll")                                                                 \
    for (int c = 0; c < 8; ++c) {                                                     \
      const uint4 hv = hp[c];                                                         \
      ar = SDOT4(Wq[0][0][c].x, hv.x, ar); ar = SDOT4(Wq[0][0][c].y, hv.y, ar);       \
      ar = SDOT4(Wq[0][0][c].z, hv.z, ar); ar = SDOT4(Wq[0][0][c].w, hv.w, ar);       \
      az = SDOT4(Wq[1][0][c].x, hv.x, az); az = SDOT4(Wq[1][0][c].y, hv.y, az);       \
      az = SDOT4(Wq[1][0][c].z, hv.z, az); az = SDOT4(Wq[1][0][c].w, hv.w, az);       \
      an = SDOT4(Wq[2][0][c].x, hv.x, an); an = SDOT4(Wq[2][0][c].y, hv.y, an);       \
      an = SDOT4(Wq[2][0][c].z, hv.z, an); an = SDOT4(Wq[2][0][c].w, hv.w, an);       \
      br = SDOT4(Wq[0][1][c].x, hv.x, br); br = SDOT4(Wq[0][1][c].y, hv.y, br);       \
      br = SDOT4(Wq[0][1][c].z, hv.z, br); br = SDOT4(Wq[0][1][c].w, hv.w, br);       \
      bz = SDOT4(Wq[1][1][c].x, hv.x, bz); bz = SDOT4(Wq[1][1][c].y, hv.y, bz);       \
      bz = SDOT4(Wq[1][1][c].z, hv.z, bz); bz = SDOT4(Wq[1][1][c].w, hv.w, bz);       \
      bn = SDOT4(Wq[2][1][c].x, hv.x, bn); bn = SDOT4(Wq[2][1][c].y, hv.y, bn);       \
      bn = SDOT4(Wq[2][1][c].z, hv.z, bn); bn = SDOT4(Wq[2][1][c].w, hv.w, bn);       \
    }                                                                                 \
    const float rA = 1.f / (1.f + __expf(-(xrA + sc[0][0] * (float)ar)));             \
    const float zA = 1.f / (1.f + __expf(-(xzA + sc[1][0] * (float)az)));             \
    const float naA = xnA + rA * (sc[2][0] * (float)an + bh2a);                       \
    const float e2A = __expf(2.f * naA);                                              \
    const float nnA = (e2A - 1.f) / (e2A + 1.f);                                      \
    const float hnA = (1.f - zA) * nnA + zA * hA;                                     \
    const float rB = 1.f / (1.f + __expf(-(xrB + sc[0][1] * (float)br)));             \
    const float zB = 1.f / (1.f + __expf(-(xzB + sc[1][1] * (float)bz)));             \
    const float naB = xnB + rB * (sc[2][1] * (float)bn + bh2b);                       \
    const float e2B = __expf(2.f * naB);                                              \
    const float nnB = (e2B - 1.f) / (e2B + 1.f);                                      \
    const float hnB = (1.f - zB) * nnB + zB * hB;                                     \
    if ((T_) < len) {                                                                 \
      hA = hnA; hB = hnB; accA += hnA; accB += hnB;                                   \
      int qa = (int)rintf(hA * 127.f), qb = (int)rintf(hB * 127.f);                   \
      ((unsigned short*)&hbw[(CUR_) ^ 1][0])[L] =                                     \
          (unsigned short)((qa & 255) | ((qb & 255) << 8));                           \
    }                                                                                 \
  }

  const int len2 = (len + 1) & ~1;
  for (int t = 0; t < len2; t += 2) {
    K2_STEP(t, 0, xa0, xa1, xa2);
    K2_STEP(t + 1, 1, xb0, xb1, xb2);
  }
#undef K2_STEP

  const float inv = 1.f / (float)len;
  *reinterpret_cast<float2*>(&mot[(size_t)b * 256 + dir * 128 + j0]) =
      make_float2(accA * inv, accB * inv);
}

// ---------------------------------------------------------------------------
// K3: out[b] = sigmoid(dot(mot[b], lin_w) + lin_b)
__global__ void k3_final(const float* __restrict__ mot, const float* __restrict__ lin_w,
                         const float* __restrict__ lin_b, float* __restrict__ out) {
  int tid = threadIdx.x;
  int b = tid >> 2, part = tid & 3;
  float s = 0.f;
  for (int i = 0; i < 64; ++i) s += mot[b * 256 + part * 64 + i] * lin_w[part * 64 + i];
  s += __shfl_xor(s, 1);
  s += __shfl_xor(s, 2);
  if (part == 0) out[b] = 1.f / (1.f + __expf(-(s + lin_b[0])));
}

// ---------------------------------------------------------------------------
extern "C" void kernel_launch(void* const* d_in, const int* in_sizes, int n_in,
                              void* d_out, int out_size, void* d_ws, size_t ws_size,
                              hipStream_t stream) {
  const int*   ipts    = (const int*)d_in[0];
  const int*   seqlen  = (const int*)d_in[1];
  const float* hidden  = (const float*)d_in[2];
  const float* emb     = (const float*)d_in[3];
  const float* conv_w  = (const float*)d_in[4];
  const float* conv_b  = (const float*)d_in[5];
  const float* w_ih_f  = (const float*)d_in[6];
  const float* w_hh_f  = (const float*)d_in[7];
  const float* b_ih_f  = (const float*)d_in[8];
  const float* b_hh_f  = (const float*)d_in[9];
  const float* w_ih_b  = (const float*)d_in[10];
  const float* w_hh_b  = (const float*)d_in[11];
  const float* b_ih_b  = (const float*)d_in[12];
  const float* b_hh_b  = (const float*)d_in[13];
  const float* lin_w   = (const float*)d_in[14];
  const float* lin_b   = (const float*)d_in[15];

  char* ws_ = (char*)d_ws;
  unsigned short* CWb = (unsigned short*)(ws_);            // 294,912 B
  float* xbias = (float*)(ws_ + 294912);                   // 3,072 B
  float* mot   = (float*)(ws_ + 298240);                   // 65,536 B
  unsigned int* Wq8 = (unsigned int*)(ws_ + 363776);       // 98,304 B
  float* wsc   = (float*)(ws_ + 462080);                   // 3,072 B
  unsigned short* xp = (unsigned short*)(ws_ + 1048576);   // 100,663,296 B (bf16)
  float* out = (float*)d_out;

  hipLaunchKernelGGL(k0_fuse, dim3(576), dim3(256), 0, stream,
                     conv_w, conv_b, w_ih_f, b_ih_f, w_ih_b, b_ih_b, b_hh_f, b_hh_b,
                     CWb, xbias);
  hipLaunchKernelGGL(k0b_quant, dim3(96), dim3(256), 0, stream,
                     w_hh_f, w_hh_b, Wq8, wsc);
  hipLaunchKernelGGL(k1_gemm, dim3(3072), dim3(256), 0, stream,
                     ipts, emb, CWb, xbias, xp);
  hipLaunchKernelGGL(k2_scan, dim3(128), dim3(64), 0, stream,
                     seqlen, hidden, b_hh_f, b_hh_b, Wq8, wsc, xp, mot);
  hipLaunchKernelGGL(k3_final, dim3(1), dim3(256), 0, stream, mot, lin_w, lin_b, out);
}

// Round 11
// 483.557 us; speedup vs baseline: 5.6390x; 1.5724x over previous
//
#include <hip/hip_runtime.h>

// V=50000, E=64, B=64, T=1024, F=128, H=128, WIN=3, PAD=1

typedef __attribute__((ext_vector_type(8))) unsigned short ushort8;
typedef __attribute__((ext_vector_type(8))) short bf16x8;
typedef __attribute__((ext_vector_type(4))) float f32x4;

__device__ __forceinline__ unsigned short f2bf(float f) {
  unsigned int u = __float_as_uint(f);
  u += 0x7fffu + ((u >> 16) & 1u);   // RNE
  return (unsigned short)(u >> 16);
}
__device__ __forceinline__ float bf2f(unsigned short us) {
  return __uint_as_float(((unsigned int)us) << 16);
}
#if __has_builtin(__builtin_amdgcn_sdot4)
#define SDOT4(a, b, c) __builtin_amdgcn_sdot4((int)(a), (int)(b), (c), false)
#else
__device__ __forceinline__ int sdot4_sw(int a, int b, int c) {
#pragma unroll
  for (int i = 0; i < 4; ++i)
    c += ((a << (24 - 8 * i)) >> 24) * ((b << (24 - 8 * i)) >> 24);
  return c;
}
#define SDOT4(a, b, c) sdot4_sw((int)(a), (int)(b), (c))
#endif
// xor-1 lane exchange via DPP quad_perm [1,0,3,2]
#define DPP_X1(x) __builtin_amdgcn_update_dpp(0, (x), 0xB1, 0xF, 0xF, true)

// ---------------------------------------------------------------------------
// K0: CWb[g][k] = bf16( sum_f Wih[g][f]*conv_w[f][k] );
//     xbias[g] = b_ih[g] + Wih[g]·conv_b (+ b_hh folded for r,z gates).
__global__ void k0_fuse(const float* __restrict__ conv_w, const float* __restrict__ conv_b,
                        const float* __restrict__ w_ih_f, const float* __restrict__ b_ih_f,
                        const float* __restrict__ w_ih_b, const float* __restrict__ b_ih_b,
                        const float* __restrict__ b_hh_f, const float* __restrict__ b_hh_b,
                        unsigned short* __restrict__ CWb, float* __restrict__ xbias) {
  int flat = blockIdx.x * 256 + threadIdx.x;
  if (flat >= 768 * 192) return;
  int g = flat / 192, k = flat % 192;
  const float* wih = (g < 384) ? w_ih_f : w_ih_b;
  int gg = (g < 384) ? g : g - 384;
  float acc = 0.f;
  for (int f = 0; f < 128; ++f) acc += wih[gg * 128 + f] * conv_w[f * 192 + k];
  CWb[g * 192 + k] = f2bf(acc);
  if (k == 0) {
    const float* bih = (g < 384) ? b_ih_f : b_ih_b;
    const float* bhh = (g < 384) ? b_hh_f : b_hh_b;
    float bb = bih[gg];
    if (gg < 256) bb += bhh[gg];   // fold hidden bias for r,z
    for (int f = 0; f < 128; ++f) bb += wih[gg * 128 + f] * conv_b[f];
    xbias[g] = bb;
  }
}

// ---------------------------------------------------------------------------
// K0b: per-row i8 quantization of W_hh (both dirs): row R = dir*384+gate*128+j.
__global__ void k0b_quant(const float* __restrict__ w_hh_f, const float* __restrict__ w_hh_b,
                          unsigned int* __restrict__ Wq8, float* __restrict__ ws) {
  int tid = blockIdx.x * 256 + threadIdx.x;
  int R = tid >> 5, dw = tid & 31;
  if (R >= 768) return;
  int dir = R / 384, rr = R - dir * 384;
  const float* w = (dir ? w_hh_b : w_hh_f) + (size_t)rr * 128 + dw * 4;
  float4 v = *reinterpret_cast<const float4*>(w);
  float am = fmaxf(fmaxf(fabsf(v.x), fabsf(v.y)), fmaxf(fabsf(v.z), fabsf(v.w)));
#pragma unroll
  for (int m = 1; m < 32; m <<= 1) am = fmaxf(am, __shfl_xor(am, m));
  float inv = (am > 0.f) ? 127.f / am : 0.f;
  int q0 = (int)rintf(v.x * inv), q1 = (int)rintf(v.y * inv);
  int q2 = (int)rintf(v.z * inv), q3 = (int)rintf(v.w * inv);
  unsigned int pk = (q0 & 255) | ((q1 & 255) << 8) | ((q2 & 255) << 16) | ((q3 & 255) << 24);
  Wq8[R * 32 + dw] = pk;
  if (dw == 0) ws[R] = am / 16129.f;
}

// ---------------------------------------------------------------------------
// K1: xp[b][t][g] = bf16( xbias[g] + sum_k A[t][k]*CW[g][k] ) via MFMA bf16.
__global__ __launch_bounds__(256) void k1_gemm(const int* __restrict__ ipts,
                                               const float* __restrict__ emb,
                                               const unsigned short* __restrict__ CWb,
                                               const float* __restrict__ xbias,
                                               unsigned short* __restrict__ xp) {
  __shared__ __align__(16) unsigned short xs[130][72];
  __shared__ __align__(16) unsigned short wsb[128][200];
  const int bid = blockIdx.x;
  const int gb = bid % 6, tb = bid / 6;
  const int b = tb >> 3, t0 = (tb & 7) << 7, g0 = gb << 7;
  const int tid = threadIdx.x;

  for (int c = tid; c < 130 * 16; c += 256) {
    int row = c >> 4, cc = c & 15;
    int t = t0 - 1 + row;
    float4 v = make_float4(0.f, 0.f, 0.f, 0.f);
    if (t >= 0 && t < 1024) {
      int tok = ipts[b * 1024 + t];
      v = *reinterpret_cast<const float4*>(emb + (size_t)tok * 64 + cc * 4);
    }
    ushort4 pv;
    pv.x = f2bf(v.x); pv.y = f2bf(v.y); pv.z = f2bf(v.z); pv.w = f2bf(v.w);
    *reinterpret_cast<ushort4*>(&xs[row][cc * 4]) = pv;
  }
  for (int c = tid; c < 128 * 24; c += 256) {
    int g = c / 24, cc = c % 24;
    *reinterpret_cast<ushort8*>(&wsb[g][cc * 8]) =
        *reinterpret_cast<const ushort8*>(CWb + (size_t)(g0 + g) * 192 + cc * 8);
  }
  __syncthreads();

  const int lane = tid & 63, wid = tid >> 6;
  const int wy = wid >> 1, wx = wid & 1;
  const int ln15 = lane & 15, lhi = lane >> 4;

  f32x4 acc[4][4];
#pragma unroll
  for (int i = 0; i < 4; ++i)
#pragma unroll
    for (int j = 0; j < 4; ++j) acc[i][j] = (f32x4){0.f, 0.f, 0.f, 0.f};

#pragma unroll
  for (int kk = 0; kk < 6; ++kk) {
    const int w = kk >> 1;
    const int e0 = (kk & 1) * 32 + lhi * 8;
    const int k0 = kk * 32 + lhi * 8;
    bf16x8 a[4], bb[4];
#pragma unroll
    for (int i = 0; i < 4; ++i)
      a[i] = *reinterpret_cast<const bf16x8*>(&xs[wy * 64 + i * 16 + ln15 + w][e0]);
#pragma unroll
    for (int j = 0; j < 4; ++j)
      bb[j] = *reinterpret_cast<const bf16x8*>(&wsb[wx * 64 + j * 16 + ln15][k0]);
#pragma unroll
    for (int i = 0; i < 4; ++i)
#pragma unroll
      for (int j = 0; j < 4; ++j)
        acc[i][j] = __builtin_amdgcn_mfma_f32_16x16x32_bf16(a[i], bb[j], acc[i][j], 0, 0, 0);
  }

  float bias[4];
#pragma unroll
  for (int j = 0; j < 4; ++j) bias[j] = xbias[g0 + wx * 64 + j * 16 + ln15];

  unsigned short* outp = xp + (size_t)(b * 1024 + t0 + wy * 64) * 768 + g0 + wx * 64;
#pragma unroll
  for (int i = 0; i < 4; ++i)
#pragma unroll
    for (int r = 0; r < 4; ++r) {
      int m = i * 16 + lhi * 4 + r;
#pragma unroll
      for (int j = 0; j < 4; ++j)
        outp[(size_t)m * 768 + j * 16 + ln15] = f2bf(acc[i][j][r] + bias[j]);
    }
}

// ---------------------------------------------------------------------------
// K2: GRU scan — one block (256 thr = 4 waves) per (batch, direction).
//     Lane tid owns (row = tid>>1, k-half = tid&1): 3 gate half-dots x 64 k
//     = 48 sdot4/lane; W_hh i8 = 48 VGPR (fits the 128-reg budget -> no AGPR
//     moves, unlike R8/R9's 192-dword plan). DPP xor1 completes each dot in
//     both pair lanes (exact int); both run the 1-row gate chain; even lane
//     publishes the i8 h-byte. h double-buffered in LDS: reads are 4x
//     ds_read_b128 (2 distinct addrs/wave = free 2-way); ONE raw s_barrier +
//     lgkmcnt(0) per step (no vmcnt drain). x: 3 global_load_ushort asm loads
//     per lane, depth-2 ring, counted vmcnt(3)+sched_barrier (rule #18).
__global__ __launch_bounds__(256, 1) void k2_scan(
    const int* __restrict__ seqlen, const float* __restrict__ hidden,
    const float* __restrict__ b_hh_f, const float* __restrict__ b_hh_b,
    const unsigned int* __restrict__ Wq8, const float* __restrict__ ws,
    const unsigned short* __restrict__ xp, float* __restrict__ mot) {
  __shared__ __align__(16) unsigned int hq[2][32];   // h as i8, double-buffered
  const int tid = threadIdx.x;
  const int b = blockIdx.x & 63, dir = blockIdx.x >> 6;
  const int row = tid >> 1;      // output row 0..127
  const int half = tid & 1;      // k-half
  const float* bhh = dir ? b_hh_b : b_hh_f;

  // --- W_hh i8: 3 gates x my 64-k half = 12 dwordx4 (48 VGPR) ---
  uint4 Wq[3][4];
#pragma unroll
  for (int g = 0; g < 3; ++g) {
    const uint4* rp = reinterpret_cast<const uint4*>(
        Wq8 + (size_t)(dir * 384 + g * 128 + row) * 32 + half * 16);
#pragma unroll
    for (int c = 0; c < 4; ++c) Wq[g][c] = rp[c];
  }
  const float sc0 = ws[dir * 384 + row];
  const float sc1 = ws[dir * 384 + 128 + row];
  const float sc2 = ws[dir * 384 + 256 + row];
  const float bh2 = bhh[256 + row];

  const int len = seqlen[b];
  float h = hidden[(size_t)(dir * 64 + b) * 128 + row];
  float acc = 0.f;
  if (!half) {
    int q = (int)rintf(h * 127.f) & 255;
    reinterpret_cast<unsigned char*>(&hq[0][0])[row] = (unsigned char)q;
  }

  // --- x-prefetch ring, depth 2 (slot A = even t, slot B = odd t) ---
  const unsigned short* xpb = xp + (size_t)b * (1024 * 768) + dir * 384 + row;
  unsigned int xa0, xa1, xa2, xb0, xb1, xb2;
  int row2;
  {
    const int r0 = dir ? (len - 1) : 0;
    const int r1 = dir ? (len - 2) : 1;            // len >= 256
    const unsigned short* q0 = xpb + (size_t)r0 * 768;
    const unsigned short* q1 = xpb + (size_t)r1 * 768;
    asm volatile("global_load_ushort %0, %1, off"            : "=v"(xa0) : "v"(q0) : "memory");
    asm volatile("global_load_ushort %0, %1, off offset:256" : "=v"(xa1) : "v"(q0) : "memory");
    asm volatile("global_load_ushort %0, %1, off offset:512" : "=v"(xa2) : "v"(q0) : "memory");
    asm volatile("global_load_ushort %0, %1, off"            : "=v"(xb0) : "v"(q1) : "memory");
    asm volatile("global_load_ushort %0, %1, off offset:256" : "=v"(xb1) : "v"(q1) : "memory");
    asm volatile("global_load_ushort %0, %1, off offset:512" : "=v"(xb2) : "v"(q1) : "memory");
    row2 = dir ? (len - 3 >= 0 ? len - 3 : 0) : (2 < len ? 2 : len - 1);
  }
  asm volatile("s_waitcnt lgkmcnt(0)" ::: "memory");
  __builtin_amdgcn_s_barrier();
  __builtin_amdgcn_sched_barrier(0);

#define K2_STEP(T_, CUR_, X0_, X1_, X2_)                                              \
  {                                                                                   \
    asm volatile("s_waitcnt vmcnt(3)" ::: "memory");                                  \
    __builtin_amdgcn_sched_barrier(0);                                                \
    const float xr = bf2f((unsigned short)(X0_));                                     \
    const float xz = bf2f((unsigned short)(X1_));                                     \
    const float xn = bf2f((unsigned short)(X2_));                                     \
    {                                                                                 \
      const unsigned short* pp = xpb + (size_t)row2 * 768;                            \
      asm volatile("global_load_ushort %0, %1, off"            : "=v"(X0_) : "v"(pp) : "memory"); \
      asm volatile("global_load_ushort %0, %1, off offset:256" : "=v"(X1_) : "v"(pp) : "memory"); \
      asm volatile("global_load_ushort %0, %1, off offset:512" : "=v"(X2_) : "v"(pp) : "memory"); \
      row2 = dir ? (row2 > 0 ? row2 - 1 : 0) : (row2 + 1 < len ? row2 + 1 : len - 1); \
    }                                                                                 \
    int ar = 0, az = 0, an = 0;                                                       \
    _Pragma("unroll")                                                                 \
    for (int c = 0; c < 4; ++c) {                                                     \
      const uint4 hv = *reinterpret_cast<const uint4*>(&hq[CUR_][half * 16 + c * 4]); \
      ar = SDOT4(Wq[0][c].x, hv.x, ar); ar = SDOT4(Wq[0][c].y, hv.y, ar);             \
      ar = SDOT4(Wq[0][c].z, hv.z, ar); ar = SDOT4(Wq[0][c].w, hv.w, ar);             \
      az = SDOT4(Wq[1][c].x, hv.x, az); az = SDOT4(Wq[1][c].y, hv.y, az);             \
      az = SDOT4(Wq[1][c].z, hv.z, az); az = SDOT4(Wq[1][c].w, hv.w, az);             \
      an = SDOT4(Wq[2][c].x, hv.x, an); an = SDOT4(Wq[2][c].y, hv.y, an);             \
      an = SDOT4(Wq[2][c].z, hv.z, an); an = SDOT4(Wq[2][c].w, hv.w, an);             \
    }                                                                                 \
    ar += DPP_X1(ar); az += DPP_X1(az); an += DPP_X1(an);                             \
    const float rr = 1.f / (1.f + __expf(-(xr + sc0 * (float)ar)));                   \
    const float zz = 1.f / (1.f + __expf(-(xz + sc1 * (float)az)));                   \
    const float na = xn + rr * (sc2 * (float)an + bh2);                               \
    const float e2 = __expf(2.f * na);                                                \
    const float nn = (e2 - 1.f) / (e2 + 1.f);                                         \
    const float hnew = (1.f - zz) * nn + zz * h;                                      \
    if ((T_) < len) {                                                                 \
      h = hnew; acc += hnew;                                                          \
      if (!half) {                                                                    \
        int q = (int)rintf(hnew * 127.f) & 255;                                       \
        reinterpret_cast<unsigned char*>(&hq[(CUR_) ^ 1][0])[row] = (unsigned char)q; \
      }                                                                               \
    }                                                                                 \
    asm volatile("s_waitcnt lgkmcnt(0)" ::: "memory");                                \
    __builtin_amdgcn_s_barrier();                                                     \
    __builtin_amdgcn_sched_barrier(0);                                                \
  }

  const int len2 = (len + 1) & ~1;
  for (int t = 0; t < len2; t += 2) {
    K2_STEP(t, 0, xa0, xa1, xa2);
    K2_STEP(t + 1, 1, xb0, xb1, xb2);
  }
#undef K2_STEP

  if (!half) mot[(size_t)b * 256 + dir * 128 + row] = acc / (float)len;
}

// ---------------------------------------------------------------------------
// K3: out[b] = sigmoid(dot(mot[b], lin_w) + lin_b)
__global__ void k3_final(const float* __restrict__ mot, const float* __restrict__ lin_w,
                         const float* __restrict__ lin_b, float* __restrict__ out) {
  int tid = threadIdx.x;
  int b = tid >> 2, part = tid & 3;
  float s = 0.f;
  for (int i = 0; i < 64; ++i) s += mot[b * 256 + part * 64 + i] * lin_w[part * 64 + i];
  s += __shfl_xor(s, 1);
  s += __shfl_xor(s, 2);
  if (part == 0) out[b] = 1.f / (1.f + __expf(-(s + lin_b[0])));
}

// ---------------------------------------------------------------------------
extern "C" void kernel_launch(void* const* d_in, const int* in_sizes, int n_in,
                              void* d_out, int out_size, void* d_ws, size_t ws_size,
                              hipStream_t stream) {
  const int*   ipts    = (const int*)d_in[0];
  const int*   seqlen  = (const int*)d_in[1];
  const float* hidden  = (const float*)d_in[2];
  const float* emb     = (const float*)d_in[3];
  const float* conv_w  = (const float*)d_in[4];
  const float* conv_b  = (const float*)d_in[5];
  const float* w_ih_f  = (const float*)d_in[6];
  const float* w_hh_f  = (const float*)d_in[7];
  const float* b_ih_f  = (const float*)d_in[8];
  const float* b_hh_f  = (const float*)d_in[9];
  const float* w_ih_b  = (const float*)d_in[10];
  const float* w_hh_b  = (const float*)d_in[11];
  const float* b_ih_b  = (const float*)d_in[12];
  const float* b_hh_b  = (const float*)d_in[13];
  const float* lin_w   = (const float*)d_in[14];
  const float* lin_b   = (const float*)d_in[15];

  char* ws_ = (char*)d_ws;
  unsigned short* CWb = (unsigned short*)(ws_);            // 294,912 B
  float* xbias = (float*)(ws_ + 294912);                   // 3,072 B
  float* mot   = (float*)(ws_ + 298240);                   // 65,536 B
  unsigned int* Wq8 = (unsigned int*)(ws_ + 363776);       // 98,304 B
  float* wsc   = (float*)(ws_ + 462080);                   // 3,072 B
  unsigned short* xp = (unsigned short*)(ws_ + 1048576);   // 100,663,296 B (bf16)
  float* out = (float*)d_out;

  hipLaunchKernelGGL(k0_fuse, dim3(576), dim3(256), 0, stream,
                     conv_w, conv_b, w_ih_f, b_ih_f, w_ih_b, b_ih_b, b_hh_f, b_hh_b,
                     CWb, xbias);
  hipLaunchKernelGGL(k0b_quant, dim3(96), dim3(256), 0, stream,
                     w_hh_f, w_hh_b, Wq8, wsc);
  hipLaunchKernelGGL(k1_gemm, dim3(3072), dim3(256), 0, stream,
                     ipts, emb, CWb, xbias, xp);
  hipLaunchKernelGGL(k2_scan, dim3(128), dim3(256), 0, stream,
                     seqlen, hidden, b_hh_f, b_hh_b, Wq8, wsc, xp, mot);
  hipLaunchKernelGGL(k3_final, dim3(1), dim3(256), 0, stream, mot, lin_w, lin_b, out);
}

// Round 12
// 483.355 us; speedup vs baseline: 5.6414x; 1.0004x over previous
//
#include <hip/hip_runtime.h>

// V=50000, E=64, B=64, T=1024, F=128, H=128, WIN=3, PAD=1

typedef __attribute__((ext_vector_type(8))) unsigned short ushort8;
typedef __attribute__((ext_vector_type(8))) short bf16x8;
typedef __attribute__((ext_vector_type(4))) float f32x4;

__device__ __forceinline__ unsigned short f2bf(float f) {
  unsigned int u = __float_as_uint(f);
  u += 0x7fffu + ((u >> 16) & 1u);   // RNE
  return (unsigned short)(u >> 16);
}
__device__ __forceinline__ float bf2f(unsigned short us) {
  return __uint_as_float(((unsigned int)us) << 16);
}
#if __has_builtin(__builtin_amdgcn_sdot4)
#define SDOT4(a, b, c) __builtin_amdgcn_sdot4((int)(a), (int)(b), (c), false)
#else
__device__ __forceinline__ int sdot4_sw(int a, int b, int c) {
#pragma unroll
  for (int i = 0; i < 4; ++i)
    c += ((a << (24 - 8 * i)) >> 24) * ((b << (24 - 8 * i)) >> 24);
  return c;
}
#define SDOT4(a, b, c) sdot4_sw((int)(a), (int)(b), (c))
#endif
// xor-1 lane exchange via DPP quad_perm [1,0,3,2]
#define DPP_X1(x) __builtin_amdgcn_update_dpp(0, (x), 0xB1, 0xF, 0xF, true)

// ---------------------------------------------------------------------------
// K0: CWb[g][k] = bf16( sum_f Wih[g][f]*conv_w[f][k] );
//     xbias[g] = b_ih[g] + Wih[g]·conv_b (+ b_hh folded for r,z gates).
__global__ void k0_fuse(const float* __restrict__ conv_w, const float* __restrict__ conv_b,
                        const float* __restrict__ w_ih_f, const float* __restrict__ b_ih_f,
                        const float* __restrict__ w_ih_b, const float* __restrict__ b_ih_b,
                        const float* __restrict__ b_hh_f, const float* __restrict__ b_hh_b,
                        unsigned short* __restrict__ CWb, float* __restrict__ xbias) {
  int flat = blockIdx.x * 256 + threadIdx.x;
  if (flat >= 768 * 192) return;
  int g = flat / 192, k = flat % 192;
  const float* wih = (g < 384) ? w_ih_f : w_ih_b;
  int gg = (g < 384) ? g : g - 384;
  float acc = 0.f;
  for (int f = 0; f < 128; ++f) acc += wih[gg * 128 + f] * conv_w[f * 192 + k];
  CWb[g * 192 + k] = f2bf(acc);
  if (k == 0) {
    const float* bih = (g < 384) ? b_ih_f : b_ih_b;
    const float* bhh = (g < 384) ? b_hh_f : b_hh_b;
    float bb = bih[gg];
    if (gg < 256) bb += bhh[gg];   // fold hidden bias for r,z
    for (int f = 0; f < 128; ++f) bb += wih[gg * 128 + f] * conv_b[f];
    xbias[g] = bb;
  }
}

// ---------------------------------------------------------------------------
// K0b: per-row i8 quantization of W_hh (both dirs): row R = dir*384+gate*128+j.
__global__ void k0b_quant(const float* __restrict__ w_hh_f, const float* __restrict__ w_hh_b,
                          unsigned int* __restrict__ Wq8, float* __restrict__ ws) {
  int tid = blockIdx.x * 256 + threadIdx.x;
  int R = tid >> 5, dw = tid & 31;
  if (R >= 768) return;
  int dir = R / 384, rr = R - dir * 384;
  const float* w = (dir ? w_hh_b : w_hh_f) + (size_t)rr * 128 + dw * 4;
  float4 v = *reinterpret_cast<const float4*>(w);
  float am = fmaxf(fmaxf(fabsf(v.x), fabsf(v.y)), fmaxf(fabsf(v.z), fabsf(v.w)));
#pragma unroll
  for (int m = 1; m < 32; m <<= 1) am = fmaxf(am, __shfl_xor(am, m));
  float inv = (am > 0.f) ? 127.f / am : 0.f;
  int q0 = (int)rintf(v.x * inv), q1 = (int)rintf(v.y * inv);
  int q2 = (int)rintf(v.z * inv), q3 = (int)rintf(v.w * inv);
  unsigned int pk = (q0 & 255) | ((q1 & 255) << 8) | ((q2 & 255) << 16) | ((q3 & 255) << 24);
  Wq8[R * 32 + dw] = pk;
  if (dw == 0) ws[R] = am / 16129.f;
}

// ---------------------------------------------------------------------------
// K1: xp[b][t][g] = bf16( xbias[g] + sum_k A[t][k]*CW[g][k] ) via MFMA bf16.
__global__ __launch_bounds__(256) void k1_gemm(const int* __restrict__ ipts,
                                               const float* __restrict__ emb,
                                               const unsigned short* __restrict__ CWb,
                                               const float* __restrict__ xbias,
                                               unsigned short* __restrict__ xp) {
  __shared__ __align__(16) unsigned short xs[130][72];
  __shared__ __align__(16) unsigned short wsb[128][200];
  const int bid = blockIdx.x;
  const int gb = bid % 6, tb = bid / 6;
  const int b = tb >> 3, t0 = (tb & 7) << 7, g0 = gb << 7;
  const int tid = threadIdx.x;

  for (int c = tid; c < 130 * 16; c += 256) {
    int row = c >> 4, cc = c & 15;
    int t = t0 - 1 + row;
    float4 v = make_float4(0.f, 0.f, 0.f, 0.f);
    if (t >= 0 && t < 1024) {
      int tok = ipts[b * 1024 + t];
      v = *reinterpret_cast<const float4*>(emb + (size_t)tok * 64 + cc * 4);
    }
    ushort4 pv;
    pv.x = f2bf(v.x); pv.y = f2bf(v.y); pv.z = f2bf(v.z); pv.w = f2bf(v.w);
    *reinterpret_cast<ushort4*>(&xs[row][cc * 4]) = pv;
  }
  for (int c = tid; c < 128 * 24; c += 256) {
    int g = c / 24, cc = c % 24;
    *reinterpret_cast<ushort8*>(&wsb[g][cc * 8]) =
        *reinterpret_cast<const ushort8*>(CWb + (size_t)(g0 + g) * 192 + cc * 8);
  }
  __syncthreads();

  const int lane = tid & 63, wid = tid >> 6;
  const int wy = wid >> 1, wx = wid & 1;
  const int ln15 = lane & 15, lhi = lane >> 4;

  f32x4 acc[4][4];
#pragma unroll
  for (int i = 0; i < 4; ++i)
#pragma unroll
    for (int j = 0; j < 4; ++j) acc[i][j] = (f32x4){0.f, 0.f, 0.f, 0.f};

#pragma unroll
  for (int kk = 0; kk < 6; ++kk) {
    const int w = kk >> 1;
    const int e0 = (kk & 1) * 32 + lhi * 8;
    const int k0 = kk * 32 + lhi * 8;
    bf16x8 a[4], bb[4];
#pragma unroll
    for (int i = 0; i < 4; ++i)
      a[i] = *reinterpret_cast<const bf16x8*>(&xs[wy * 64 + i * 16 + ln15 + w][e0]);
#pragma unroll
    for (int j = 0; j < 4; ++j)
      bb[j] = *reinterpret_cast<const bf16x8*>(&wsb[wx * 64 + j * 16 + ln15][k0]);
#pragma unroll
    for (int i = 0; i < 4; ++i)
#pragma unroll
      for (int j = 0; j < 4; ++j)
        acc[i][j] = __builtin_amdgcn_mfma_f32_16x16x32_bf16(a[i], bb[j], acc[i][j], 0, 0, 0);
  }

  float bias[4];
#pragma unroll
  for (int j = 0; j < 4; ++j) bias[j] = xbias[g0 + wx * 64 + j * 16 + ln15];

  unsigned short* outp = xp + (size_t)(b * 1024 + t0 + wy * 64) * 768 + g0 + wx * 64;
#pragma unroll
  for (int i = 0; i < 4; ++i)
#pragma unroll
    for (int r = 0; r < 4; ++r) {
      int m = i * 16 + lhi * 4 + r;
#pragma unroll
      for (int j = 0; j < 4; ++j)
        outp[(size_t)m * 768 + j * 16 + ln15] = f2bf(acc[i][j][r] + bias[j]);
    }
}

// ---------------------------------------------------------------------------
// K2: GRU scan — one block (256 thr = 4 waves) per (batch, direction).
//     Lane tid owns (row = tid>>1, k-half = tid&1): 3 gate half-dots x 64 k
//     = 48 sdot4/lane. W_hh i8 loaded via VOLATILE ASM dwordx4 -> cannot be
//     rematerialized, forced VGPR-resident (48 + ~40 working regs; R11's
//     plain loads were re-fetched from L2 every step = ~300 cyc on the serial
//     path, VGPR_Count 40 proved non-residency). Manual vmcnt(0) drain after
//     the W prologue (asm outputs have no compiler dep tracking), THEN the
//     x-ring is issued so in-loop vmcnt(3) counts only ring loads.
//     DPP xor1 completes each dot in both pair lanes; both run the 1-row
//     gate chain; even lane publishes the i8 h-byte. h double-buffered in
//     LDS; ONE raw s_barrier + lgkmcnt(0) per step (no vmcnt drain).
__global__ __launch_bounds__(256, 1) void k2_scan(
    const int* __restrict__ seqlen, const float* __restrict__ hidden,
    const float* __restrict__ b_hh_f, const float* __restrict__ b_hh_b,
    const unsigned int* __restrict__ Wq8, const float* __restrict__ ws,
    const unsigned short* __restrict__ xp, float* __restrict__ mot) {
  __shared__ __align__(16) unsigned int hq[2][32];   // h as i8, double-buffered
  const int tid = threadIdx.x;
  const int b = blockIdx.x & 63, dir = blockIdx.x >> 6;
  const int row = tid >> 1;      // output row 0..127
  const int half = tid & 1;      // k-half
  const float* bhh = dir ? b_hh_b : b_hh_f;

  // --- W_hh i8: 3 gates x my 64-k half = 12 dwordx4 via volatile asm (48 VGPR) ---
  uint4 Wq[3][4];
#pragma unroll
  for (int g = 0; g < 3; ++g) {
    const uint4* rp = reinterpret_cast<const uint4*>(
        Wq8 + (size_t)(dir * 384 + g * 128 + row) * 32 + half * 16);
#pragma unroll
    for (int c = 0; c < 4; ++c)
      asm volatile("global_load_dwordx4 %0, %1, off"
                   : "=v"(Wq[g][c]) : "v"(rp + c) : "memory");
  }
  // drain W loads NOW (before any other VMEM) — asm outputs have no dep tracking
  asm volatile("s_waitcnt vmcnt(0)" ::: "memory");
  __builtin_amdgcn_sched_barrier(0);

  const float sc0 = ws[dir * 384 + row];
  const float sc1 = ws[dir * 384 + 128 + row];
  const float sc2 = ws[dir * 384 + 256 + row];
  const float bh2 = bhh[256 + row];

  const int len = seqlen[b];
  float h = hidden[(size_t)(dir * 64 + b) * 128 + row];
  float acc = 0.f;
  if (!half) {
    int q = (int)rintf(h * 127.f) & 255;
    reinterpret_cast<unsigned char*>(&hq[0][0])[row] = (unsigned char)q;
  }

  // --- x-prefetch ring, depth 2 (slot A = even t, slot B = odd t) ---
  const unsigned short* xpb = xp + (size_t)b * (1024 * 768) + dir * 384 + row;
  unsigned int xa0, xa1, xa2, xb0, xb1, xb2;
  int row2;
  {
    const int r0 = dir ? (len - 1) : 0;
    const int r1 = dir ? (len - 2) : 1;            // len >= 256
    const unsigned short* q0 = xpb + (size_t)r0 * 768;
    const unsigned short* q1 = xpb + (size_t)r1 * 768;
    asm volatile("global_load_ushort %0, %1, off"            : "=v"(xa0) : "v"(q0) : "memory");
    asm volatile("global_load_ushort %0, %1, off offset:256" : "=v"(xa1) : "v"(q0) : "memory");
    asm volatile("global_load_ushort %0, %1, off offset:512" : "=v"(xa2) : "v"(q0) : "memory");
    asm volatile("global_load_ushort %0, %1, off"            : "=v"(xb0) : "v"(q1) : "memory");
    asm volatile("global_load_ushort %0, %1, off offset:256" : "=v"(xb1) : "v"(q1) : "memory");
    asm volatile("global_load_ushort %0, %1, off offset:512" : "=v"(xb2) : "v"(q1) : "memory");
    row2 = dir ? (len - 3 >= 0 ? len - 3 : 0) : (2 < len ? 2 : len - 1);
  }
  asm volatile("s_waitcnt lgkmcnt(0)" ::: "memory");
  __builtin_amdgcn_s_barrier();
  __builtin_amdgcn_sched_barrier(0);

#define K2_STEP(T_, CUR_, X0_, X1_, X2_)                                              \
  {                                                                                   \
    asm volatile("s_waitcnt vmcnt(3)" ::: "memory");                                  \
    __builtin_amdgcn_sched_barrier(0);                                                \
    const float xr = bf2f((unsigned short)(X0_));                                     \
    const float xz = bf2f((unsigned short)(X1_));                                     \
    const float xn = bf2f((unsigned short)(X2_));                                     \
    {                                                                                 \
      const unsigned short* pp = xpb + (size_t)row2 * 768;                            \
      asm volatile("global_load_ushort %0, %1, off"            : "=v"(X0_) : "v"(pp) : "memory"); \
      asm volatile("global_load_ushort %0, %1, off offset:256" : "=v"(X1_) : "v"(pp) : "memory"); \
      asm volatile("global_load_ushort %0, %1, off offset:512" : "=v"(X2_) : "v"(pp) : "memory"); \
      row2 = dir ? (row2 > 0 ? row2 - 1 : 0) : (row2 + 1 < len ? row2 + 1 : len - 1); \
    }                                                                                 \
    int ar = 0, az = 0, an = 0;                                                       \
    _Pragma("unroll")                                                                 \
    for (int c = 0; c < 4; ++c) {                                                     \
      const uint4 hv = *reinterpret_cast<const uint4*>(&hq[CUR_][half * 16 + c * 4]); \
      ar = SDOT4(Wq[0][c].x, hv.x, ar); ar = SDOT4(Wq[0][c].y, hv.y, ar);             \
      ar = SDOT4(Wq[0][c].z, hv.z, ar); ar = SDOT4(Wq[0][c].w, hv.w, ar);             \
      az = SDOT4(Wq[1][c].x, hv.x, az); az = SDOT4(Wq[1][c].y, hv.y, az);             \
      az = SDOT4(Wq[1][c].z, hv.z, az); az = SDOT4(Wq[1][c].w, hv.w, az);             \
      an = SDOT4(Wq[2][c].x, hv.x, an); an = SDOT4(Wq[2][c].y, hv.y, an);             \
      an = SDOT4(Wq[2][c].z, hv.z, an); an = SDOT4(Wq[2][c].w, hv.w, an);             \
    }                                                                                 \
    ar += DPP_X1(ar); az += DPP_X1(az); an += DPP_X1(an);                             \
    const float rr = 1.f / (1.f + __expf(-(xr + sc0 * (float)ar)));                   \
    const float zz = 1.f / (1.f + __expf(-(xz + sc1 * (float)az)));                   \
    const float na = xn + rr * (sc2 * (float)an + bh2);                               \
    const float e2 = __expf(2.f * na);                                                \
    const float nn = (e2 - 1.f) / (e2 + 1.f);                                         \
    const float hnew = (1.f - zz) * nn + zz * h;                                      \
    if ((T_) < len) {                                                                 \
      h = hnew; acc += hnew;                                                          \
      if (!half) {                                                                    \
        int q = (int)rintf(hnew * 127.f) & 255;                                       \
        reinterpret_cast<unsigned char*>(&hq[(CUR_) ^ 1][0])[row] = (unsigned char)q; \
      }                                                                               \
    }                                                                                 \
    asm volatile("s_waitcnt lgkmcnt(0)" ::: "memory");                                \
    __builtin_amdgcn_s_barrier();                                                     \
    __builtin_amdgcn_sched_barrier(0);                                                \
  }

  const int len2 = (len + 1) & ~1;
  for (int t = 0; t < len2; t += 2) {
    K2_STEP(t, 0, xa0, xa1, xa2);
    K2_STEP(t + 1, 1, xb0, xb1, xb2);
  }
#undef K2_STEP

  if (!half) mot[(size_t)b * 256 + dir * 128 + row] = acc / (float)len;
}

// ---------------------------------------------------------------------------
// K3: out[b] = sigmoid(dot(mot[b], lin_w) + lin_b)
__global__ void k3_final(const float* __restrict__ mot, const float* __restrict__ lin_w,
                         const float* __restrict__ lin_b, float* __restrict__ out) {
  int tid = threadIdx.x;
  int b = tid >> 2, part = tid & 3;
  float s = 0.f;
  for (int i = 0; i < 64; ++i) s += mot[b * 256 + part * 64 + i] * lin_w[part * 64 + i];
  s += __shfl_xor(s, 1);
  s += __shfl_xor(s, 2);
  if (part == 0) out[b] = 1.f / (1.f + __expf(-(s + lin_b[0])));
}

// ---------------------------------------------------------------------------
extern "C" void kernel_launch(void* const* d_in, const int* in_sizes, int n_in,
                              void* d_out, int out_size, void* d_ws, size_t ws_size,
                              hipStream_t stream) {
  const int*   ipts    = (const int*)d_in[0];
  const int*   seqlen  = (const int*)d_in[1];
  const float* hidden  = (const float*)d_in[2];
  const float* emb     = (const float*)d_in[3];
  const float* conv_w  = (const float*)d_in[4];
  const float* conv_b  = (const float*)d_in[5];
  const float* w_ih_f  = (const float*)d_in[6];
  const float* w_hh_f  = (const float*)d_in[7];
  const float* b_ih_f  = (const float*)d_in[8];
  const float* b_hh_f  = (const float*)d_in[9];
  const float* w_ih_b  = (const float*)d_in[10];
  const float* w_hh_b  = (const float*)d_in[11];
  const float* b_ih_b  = (const float*)d_in[12];
  const float* b_hh_b  = (const float*)d_in[13];
  const float* lin_w   = (const float*)d_in[14];
  const float* lin_b   = (const float*)d_in[15];

  char* ws_ = (char*)d_ws;
  unsigned short* CWb = (unsigned short*)(ws_);            // 294,912 B
  float* xbias = (float*)(ws_ + 294912);                   // 3,072 B
  float* mot   = (float*)(ws_ + 298240);                   // 65,536 B
  unsigned int* Wq8 = (unsigned int*)(ws_ + 363776);       // 98,304 B
  float* wsc   = (float*)(ws_ + 462080);                   // 3,072 B
  unsigned short* xp = (unsigned short*)(ws_ + 1048576);   // 100,663,296 B (bf16)
  float* out = (float*)d_out;

  hipLaunchKernelGGL(k0_fuse, dim3(576), dim3(256), 0, stream,
                     conv_w, conv_b, w_ih_f, b_ih_f, w_ih_b, b_ih_b, b_hh_f, b_hh_b,
                     CWb, xbias);
  hipLaunchKernelGGL(k0b_quant, dim3(96), dim3(256), 0, stream,
                     w_hh_f, w_hh_b, Wq8, wsc);
  hipLaunchKernelGGL(k1_gemm, dim3(3072), dim3(256), 0, stream,
                     ipts, emb, CWb, xbias, xp);
  hipLaunchKernelGGL(k2_scan, dim3(128), dim3(256), 0, stream,
                     seqlen, hidden, b_hh_f, b_hh_b, Wq8, wsc, xp, mot);
  hipLaunchKernelGGL(k3_final, dim3(1), dim3(256), 0, stream, mot, lin_w, lin_b, out);
}